// Round 5
// baseline (1752.692 us; speedup 1.0000x reference)
//
#include <hip/hip_runtime.h>
#include <math.h>

#define B_   128
#define L_   256
#define DW_  100
#define DC_  30
#define HD_  200
#define NT_  18
#define SG   4     // batches per scan block
#define KP0  160   // padded K for layer-0 GEMM (130 -> 160)
#define KP1  416   // padded K for layer-1 GEMM (400 -> 416)

typedef _Float16 half8 __attribute__((ext_vector_type(8)));
typedef _Float16 half4 __attribute__((ext_vector_type(4)));
typedef float    f32x4 __attribute__((ext_vector_type(4)));

__device__ __forceinline__ float frcp_(float x) { return __builtin_amdgcn_rcpf(x); }
__device__ __forceinline__ float sigm_(float x) { return frcp_(1.0f + __expf(-x)); }
__device__ __forceinline__ float tanh_(float x) { return 1.0f - 2.0f * frcp_(1.0f + __expf(2.0f * x)); }

// ---------------- embedding gather -> fp16 x (B*L, KP0), pads zeroed
__global__ void k_embed(const int* __restrict__ words, const int* __restrict__ caps,
                        const float* __restrict__ wemb, const float* __restrict__ cemb,
                        _Float16* __restrict__ x) {
    int pos = blockIdx.x;
    int w = words[pos], c = caps[pos];
    _Float16* xp = x + (size_t)pos * KP0;
    for (int t = threadIdx.x; t < KP0; t += blockDim.x) {
        float v = 0.f;
        if (t < DW_) v = wemb[(size_t)w * DW_ + t];
        else if (t < DW_ + DC_) v = cemb[(size_t)c * DC_ + (t - DW_)];
        xp[t] = (_Float16)v;
    }
}

// ---------------- W_ih prep: src (800,K) fp32 -> dst fp16 (1600, Kpad), col = colOff + 4*jh + g
__global__ void k_perm_ih16(const float* __restrict__ src, _Float16* __restrict__ dst,
                            int K, int Kpad, int colOff) {
    int i = blockIdx.x * blockDim.x + threadIdx.x;
    if (i >= 800 * Kpad) return;
    int r = i / Kpad, k = i - r * Kpad;
    int jh = r % 200, g = r / 200;
    int col = colOff + (jh << 2) + g;
    dst[(size_t)col * Kpad + k] = (k < K) ? (_Float16)src[(size_t)r * K + k] : (_Float16)0.f;
}

__global__ void k_bias_perm(const float* bi_f, const float* bh_f,
                            const float* bi_b, const float* bh_b, float* bias) {
    int j = blockIdx.x * blockDim.x + threadIdx.x;
    if (j >= 1600) return;
    int dir = j / 800, r = j - dir * 800;
    int col = dir * 800 + ((r % 200) << 2) + (r / 200);
    bias[col] = dir ? (bi_b[r] + bh_b[r]) : (bi_f[r] + bh_f[r]);
}

__global__ void k_wlog(const float* __restrict__ Wf, const float* __restrict__ bfv,
                       const float* __restrict__ Wb, const float* __restrict__ bbv,
                       float* __restrict__ wlog, float* __restrict__ blog) {
    int i = blockIdx.x * blockDim.x + threadIdx.x;
    if (i < NT_ * 400) {
        int t = i / 400, k = i - t * 400;
        wlog[i] = (k < HD_) ? Wf[t * HD_ + k] : Wb[t * HD_ + (k - HD_)];
    }
    if (i < NT_) blog[i] = bfv[i] + bbv[i];
}

// ---------------- MFMA fp16 GEMM: C(M,1600) = A(M,Kpad) @ Bt(1600,Kpad)^T + bias
__global__ __launch_bounds__(256) void k_gemm16(const _Float16* __restrict__ A,
                                                const _Float16* __restrict__ Bt,
                                                const float* __restrict__ bias,
                                                _Float16* __restrict__ C,
                                                int Kpad) {
    __shared__ __align__(16) _Float16 sA[128 * 40];
    __shared__ __align__(16) _Float16 sB[64 * 40];
    const int tid = threadIdx.x;
    const int w = tid >> 6, l = tid & 63, l15 = l & 15, lq = l >> 4;
    const int m0 = blockIdx.y * 128, n0 = blockIdx.x * 64;
    const int rw = (w >> 1) * 64, cw = (w & 1) * 32;
    f32x4 acc[4][2];
    #pragma unroll
    for (int i = 0; i < 4; i++)
        #pragma unroll
        for (int j = 0; j < 2; j++) acc[i][j] = f32x4{0.f, 0.f, 0.f, 0.f};

    for (int k0 = 0; k0 < Kpad; k0 += 32) {
        {
            int m = tid >> 1, c = (tid & 1) << 4;
            const _Float16* ap = A + (size_t)(m0 + m) * Kpad + k0 + c;
            *(half8*)&sA[m * 40 + c]     = *(const half8*)ap;
            *(half8*)&sA[m * 40 + c + 8] = *(const half8*)(ap + 8);
        }
        {
            int n = tid >> 2, k8 = (tid & 3) << 3;
            *(half8*)&sB[n * 40 + k8] = *(const half8*)&Bt[(size_t)(n0 + n) * Kpad + k0 + k8];
        }
        __syncthreads();
        half8 aF[4], bF[2];
        #pragma unroll
        for (int i = 0; i < 4; i++) aF[i] = *(const half8*)&sA[(rw + i * 16 + l15) * 40 + lq * 8];
        #pragma unroll
        for (int j = 0; j < 2; j++) bF[j] = *(const half8*)&sB[(cw + j * 16 + l15) * 40 + lq * 8];
        #pragma unroll
        for (int i = 0; i < 4; i++)
            #pragma unroll
            for (int j = 0; j < 2; j++)
                acc[i][j] = __builtin_amdgcn_mfma_f32_16x16x32_f16(aF[i], bF[j], acc[i][j], 0, 0, 0);
        __syncthreads();
    }
    #pragma unroll
    for (int j = 0; j < 2; j++) {
        int n = n0 + cw + j * 16 + l15;
        float bv = bias[n];
        #pragma unroll
        for (int i = 0; i < 4; i++) {
            int mrow = m0 + rw + i * 16 + lq * 4;
            #pragma unroll
            for (int r = 0; r < 4; r++)
                C[(size_t)(mrow + r) * 1600 + n] = (_Float16)(acc[i][j][r] + bv);
        }
    }
}

// ---------------- MFMA LSTM scan v5: transposed orientation D = W @ h^T.
// D col = batch (lane&15, 4 valid), row = 4*jh + gate -> each active lane holds
// all 4 gates of one cell in its 4 accumulator regs. No gate-sum LDS round-trip.
// gates: (B,L,1600) fp16, cols = dir*800 + 4*h + gate(i,f,g,o)
// hout: fp16 (B*L, ldH); dir0 -> cols [0,200), dir1 -> [200,400); masked
__global__ __launch_bounds__(512, 2) void k_scan5(const _Float16* __restrict__ gates,
                                                  const float* __restrict__ Whh_f,
                                                  const float* __restrict__ Whh_b,
                                                  const int* __restrict__ seq_len,
                                                  _Float16* __restrict__ hout, int ldH) {
    const int dir = blockIdx.x & 1;
    const int b0  = (blockIdx.x >> 1) * SG;
    const int tid = threadIdx.x;
    const int w   = tid >> 6;
    const int l   = tid & 63;
    const int l15 = l & 15;
    const int lq  = l >> 4;

    __shared__ __align__(16) _Float16 hA[2][16 * 232];   // ping-pong h state [p][m*232+k]
    __shared__ __align__(16) _Float16 bEx[2 * 7 * 512];  // W-frags tiles 48,49
    __shared__ __align__(16) _Float16 glds[2][3200];     // staged gates [buf][m*800 + col]
    __shared__ int ssl[SG];

    const float* W = dir ? Whh_b : Whh_f;
    const int nT = (w < 2) ? 7 : 6;

    // resident W-fragments: 6 register tiles per wave + tiles 48/49 in LDS (waves 0,1)
    // lane l15 = W-row-within-tile, k = lq*8+j  (A-operand layout)
    half8 Breg[6][7];
    #pragma unroll
    for (int i = 0; i < 6; i++) {
        int n  = (w * 6 + i) * 16 + l15;
        int jh = n >> 2, g = n & 3;
        const float* Wr = W + (size_t)(g * 200 + jh) * 200;
        #pragma unroll
        for (int kt = 0; kt < 7; kt++) {
            int k0 = kt * 32 + lq * 8;
            half8 f;
            #pragma unroll
            for (int j = 0; j < 8; j++) {
                int k = k0 + j;
                f[j] = (k < 200) ? (_Float16)Wr[k] : (_Float16)0.f;
            }
            Breg[i][kt] = f;
        }
    }
    if (w < 2) {
        int n  = (48 + w) * 16 + l15;
        int jh = n >> 2, g = n & 3;
        const float* Wr = W + (size_t)(g * 200 + jh) * 200;
        for (int kt = 0; kt < 7; kt++) {
            int k0 = kt * 32 + lq * 8;
            half8 f;
            for (int j = 0; j < 8; j++) {
                int k = k0 + j;
                f[j] = (k < 200) ? (_Float16)Wr[k] : (_Float16)0.f;
            }
            *(half8*)&bEx[(w * 7 + kt) * 512 + l * 8] = f;
        }
    }
    for (int i = tid; i < 2 * 16 * 232; i += 512) (&hA[0][0])[i] = (_Float16)0.f;
    if (tid < SG) ssl[tid] = seq_len[b0 + tid];

    // staging lane identity: lane v stages 16B of row m_st
    const int  v    = tid;
    const bool stv  = v < 400;
    const int  m_st = v / 100;
    const int  u_st = v - m_st * 100;
    const int  sl_st = stv ? seq_len[b0 + m_st] : L_;
    const _Float16* gbase_st = gates + ((size_t)(b0 + m_st) * L_) * 1600 + dir * 800 + u_st * 8;

    // cell identity (transposed D): active lanes l15 < 4; m = l15, sub-hidden = lq
    const bool act = (l15 < 4);
    const int  m   = l15;
    int hcol[7];
    #pragma unroll
    for (int i = 0; i < 7; i++) {
        int tile = (i < 6) ? (w * 6 + i) : (48 + w);
        hcol[i] = tile * 4 + lq;        // hidden index owned in slot i
    }
    float cs[7];
    #pragma unroll
    for (int i = 0; i < 7; i++) cs[i] = 0.f;

    // stage t=0
    if (stv) {
        int rn = dir ? ((sl_st > 0) ? sl_st - 1 : 0) : 0;
        half8 stg = *(const half8*)(gbase_st + (size_t)rn * 1600);
        *(half8*)&glds[0][v * 8] = stg;
    }
    __syncthreads();

    const f32x4 Cz = {0.f, 0.f, 0.f, 0.f};
    for (int t = 0; t < L_; t++) {
        const int p = t & 1;

        // issue staging load for t+1 (committed to LDS at end of step)
        half8 stgn;
        const bool doStg = stv && (t + 1 < L_);
        if (doStg) {
            int tn = t + 1;
            int rn = dir ? ((tn < sl_st) ? sl_st - 1 - tn : tn) : tn;
            stgn = *(const half8*)(gbase_st + (size_t)rn * 1600);
        }

        // coalesced writeback of h(t-1) from hA[p]: 400 lanes x 1 dword
        if (t > 0 && stv) {
            int tp = t - 1;
            int b  = m_st;              // reuse v-decomposition: b = v/100
            int hp = u_st;              // dword index within row: halfs 2hp, 2hp+1
            int slb = ssl[b];
            int row = dir ? ((tp < slb) ? slb - 1 - tp : tp) : tp;
            unsigned int val = (tp < slb) ? *(const unsigned int*)&hA[p][b * 232 + 2 * hp] : 0u;
            *(unsigned int*)&hout[((size_t)(b0 + b) * L_ + row) * ldH + dir * HD_ + 2 * hp] = val;
        }

        // MFMA: D = W @ h(t-1)^T  (A = W-frag, B = h-frag)
        f32x4 C[7];
        #pragma unroll
        for (int i = 0; i < 7; i++) C[i] = Cz;
        #pragma unroll
        for (int kt = 0; kt < 7; kt++) {
            half8 hF = *(const half8*)&hA[p][l15 * 232 + kt * 32 + lq * 8];
            #pragma unroll
            for (int i = 0; i < 6; i++)
                C[i] = __builtin_amdgcn_mfma_f32_16x16x32_f16(Breg[i][kt], hF, C[i], 0, 0, 0);
            if (w < 2) {
                half8 bF = *(const half8*)&bEx[(w * 7 + kt) * 512 + l * 8];
                C[6] = __builtin_amdgcn_mfma_f32_16x16x32_f16(bF, hF, C[6], 0, 0, 0);
            }
        }

        // nonlinearity: active lane holds gates i,f,g,o of cell (hcol[i], m) in C[i][0..3]
        if (act) {
            #pragma unroll
            for (int i = 0; i < 7; i++) if (i < nT) {
                half4 gi4 = *(const half4*)&glds[p][m * 800 + 4 * hcol[i]];
                float xi = C[i][0] + (float)gi4[0];
                float xf = C[i][1] + (float)gi4[1];
                float xg = C[i][2] + (float)gi4[2];
                float xo = C[i][3] + (float)gi4[3];
                float cn = sigm_(xf) * cs[i] + sigm_(xi) * tanh_(xg);
                cs[i] = cn;
                hA[1 - p][m * 232 + hcol[i]] = (_Float16)(sigm_(xo) * tanh_(cn));
            }
        }

        // commit staged gates for t+1
        if (doStg) *(half8*)&glds[1 - p][v * 8] = stgn;

        __syncthreads();
    }
    // epilogue: write back h(L-1) from hA[0]
    if (stv) {
        int tp = L_ - 1;
        int b  = m_st;
        int hp = u_st;
        int slb = ssl[b];
        int row = dir ? ((tp < slb) ? slb - 1 - tp : tp) : tp;
        unsigned int val = (tp < slb) ? *(const unsigned int*)&hA[0][b * 232 + 2 * hp] : 0u;
        *(unsigned int*)&hout[((size_t)(b0 + b) * L_ + row) * ldH + dir * HD_ + 2 * hp] = val;
    }
}

// ---------------- logits: (B*L,18) = h1(B*L,400 fp16) @ wlog^T + blog
__global__ __launch_bounds__(256) void k_logits(const _Float16* __restrict__ h1,
                                                const float* __restrict__ wlog,
                                                const float* __restrict__ blog,
                                                float* __restrict__ logits) {
    __shared__ float sh[8][400];
    __shared__ float sw[NT_ * 400];
    int p0 = blockIdx.x * 8;
    for (int i = threadIdx.x; i < 8 * 400; i += 256)
        sh[i / 400][i % 400] = (float)h1[(size_t)p0 * 400 + i];
    for (int i = threadIdx.x; i < NT_ * 400; i += 256) sw[i] = wlog[i];
    __syncthreads();
    if (threadIdx.x < 8 * NT_) {
        int pi = threadIdx.x / NT_, tg = threadIdx.x % NT_;
        float a = blog[tg];
        #pragma unroll 4
        for (int k = 0; k < 400; k++) a += sh[pi][k] * sw[tg * 400 + k];
        logits[((size_t)(p0 + pi)) * NT_ + tg] = a;
    }
}

// ---------------- CRF NLL per batch row
__global__ __launch_bounds__(64) void k_crf(const float* __restrict__ logits,
                                            const int* __restrict__ target,
                                            const int* __restrict__ seq_len,
                                            const float* __restrict__ trans,
                                            float* __restrict__ out) {
    int b = blockIdx.x, tid = threadIdx.x;
    __shared__ float str[NT_ * NT_];
    __shared__ float alpha[NT_];
    __shared__ float sgold[1];
    for (int i = tid; i < NT_ * NT_; i += 64) str[i] = trans[i];
    int sl = seq_len[b];
    const float* lg = logits + (size_t)b * L_ * NT_;
    const int* tg = target + (size_t)b * L_;
    if (tid < NT_) alpha[tid] = lg[tid];
    float gacc = 0.f;
    for (int t = tid; t < L_; t += 64) {
        if (t < sl) {
            gacc += lg[t * NT_ + tg[t]];
            if (t >= 1) gacc += trans[tg[t - 1] * NT_ + tg[t]];
        }
    }
    #pragma unroll
    for (int off = 32; off; off >>= 1) gacc += __shfl_down(gacc, off);
    if (tid == 0) sgold[0] = gacc;
    __syncthreads();
    for (int t = 1; t < L_; t++) {
        if (t < sl) {
            float v = 0.f;
            if (tid < NT_) {
                float mx = -1e30f;
                #pragma unroll
                for (int i = 0; i < NT_; i++) mx = fmaxf(mx, alpha[i] + str[i * NT_ + tid]);
                float s = 0.f;
                #pragma unroll
                for (int i = 0; i < NT_; i++) s += __expf(alpha[i] + str[i * NT_ + tid] - mx);
                v = mx + __logf(s) + lg[t * NT_ + tid];
            }
            __syncthreads();
            if (tid < NT_) alpha[tid] = v;
            __syncthreads();
        }
    }
    if (tid == 0) {
        float mx = -1e30f;
        for (int i = 0; i < NT_; i++) mx = fmaxf(mx, alpha[i]);
        float s = 0.f;
        for (int i = 0; i < NT_; i++) s += __expf(alpha[i] - mx);
        out[b] = (mx + __logf(s)) - sgold[0];
    }
}

extern "C" void kernel_launch(void* const* d_in, const int* in_sizes, int n_in,
                              void* d_out, int out_size, void* d_ws, size_t ws_size,
                              hipStream_t stream) {
    const int*   words  = (const int*)d_in[0];
    const int*   caps   = (const int*)d_in[1];
    const int*   seq    = (const int*)d_in[2];
    const int*   target = (const int*)d_in[3];
    const float* wemb   = (const float*)d_in[4];
    const float* cemb   = (const float*)d_in[5];
    const float* Wih0f  = (const float*)d_in[6];
    const float* Whh0f  = (const float*)d_in[7];
    const float* bih0f  = (const float*)d_in[8];
    const float* bhh0f  = (const float*)d_in[9];
    const float* Wih0b  = (const float*)d_in[10];
    const float* Whh0b  = (const float*)d_in[11];
    const float* bih0b  = (const float*)d_in[12];
    const float* bhh0b  = (const float*)d_in[13];
    const float* Wih1f  = (const float*)d_in[14];
    const float* Whh1f  = (const float*)d_in[15];
    const float* bih1f  = (const float*)d_in[16];
    const float* bhh1f  = (const float*)d_in[17];
    const float* Wih1b  = (const float*)d_in[18];
    const float* Whh1b  = (const float*)d_in[19];
    const float* bih1b  = (const float*)d_in[20];
    const float* bhh1b  = (const float*)d_in[21];
    const float* Wf     = (const float*)d_in[22];
    const float* bfv    = (const float*)d_in[23];
    const float* Wb     = (const float*)d_in[24];
    const float* bbv    = (const float*)d_in[25];
    const float* trans  = (const float*)d_in[26];

    char* base = (char*)d_ws;
    _Float16* gatesH = (_Float16*)(base + 0);                 // 104,857,600 B (32768x1600)
    _Float16* xbuf   = (_Float16*)(base + 104857600);         // 10,485,760 B (32768x160)
    _Float16* h0b    = (_Float16*)(base + 115343360);         // 27,262,976 B (32768x416)
    _Float16* h1b    = xbuf;  // 26,214,400 B needed; xbuf+h0 region dead by then
    float* logitsb   = (float*)(base + 142606336);            // 2,359,296 B
    _Float16* wihT0  = (_Float16*)(base + 144965632);         // 512,000 B (1600x160)
    _Float16* wihT1  = (_Float16*)(base + 145477632);         // 1,331,200 B (1600x416)
    float* bias0     = (float*)(base + 146808832);            // 6,400 B
    float* bias1     = (float*)(base + 146815232);            // 6,400 B
    float* wlog      = (float*)(base + 146821632);            // 28,800 B
    float* blog      = (float*)(base + 146850432);            // 128 B

    // --- weight prep
    k_perm_ih16<<<(800 * KP0 + 255) / 256, 256, 0, stream>>>(Wih0f, wihT0, 130, KP0, 0);
    k_perm_ih16<<<(800 * KP0 + 255) / 256, 256, 0, stream>>>(Wih0b, wihT0, 130, KP0, 800);
    k_perm_ih16<<<(800 * KP1 + 255) / 256, 256, 0, stream>>>(Wih1f, wihT1, 400, KP1, 0);
    k_perm_ih16<<<(800 * KP1 + 255) / 256, 256, 0, stream>>>(Wih1b, wihT1, 400, KP1, 800);
    k_bias_perm<<<7, 256, 0, stream>>>(bih0f, bhh0f, bih0b, bhh0b, bias0);
    k_bias_perm<<<7, 256, 0, stream>>>(bih1f, bhh1f, bih1b, bhh1b, bias1);
    k_wlog<<<(NT_ * 400 + 255) / 256, 256, 0, stream>>>(Wf, bfv, Wb, bbv, wlog, blog);

    // --- embeddings (fp16, padded)
    k_embed<<<B_ * L_, 128, 0, stream>>>(words, caps, wemb, cemb, xbuf);

    // zero h0 (its K-pad cols 400..415 must be 0 for the layer-1 GEMM)
    hipMemsetAsync(h0b, 0, (size_t)32768 * KP1 * sizeof(_Float16), stream);

    // --- layer 0
    k_gemm16<<<dim3(25, 256), 256, 0, stream>>>(xbuf, wihT0, bias0, gatesH, KP0);
    k_scan5<<<(B_ / SG) * 2, 512, 0, stream>>>(gatesH, Whh0f, Whh0b, seq, h0b, KP1);

    // --- layer 1
    k_gemm16<<<dim3(25, 256), 256, 0, stream>>>(h0b, wihT1, bias1, gatesH, KP1);
    k_scan5<<<(B_ / SG) * 2, 512, 0, stream>>>(gatesH, Whh1f, Whh1b, seq, h1b, 400);

    // --- logits + CRF
    k_logits<<<(B_ * L_) / 8, 256, 0, stream>>>(h1b, wlog, blog, logitsb);
    k_crf<<<B_, 64, 0, stream>>>(logitsb, target, seq, trans, (float*)d_out);
}

// Round 6
// 1472.627 us; speedup vs baseline: 1.1902x; 1.1902x over previous
//
#include <hip/hip_runtime.h>
#include <math.h>

#define B_   128
#define L_   256
#define DW_  100
#define DC_  30
#define HD_  200
#define NT_  18
#define SG   4     // batches per scan block
#define KP0  160   // padded K for layer-0 GEMM (130 -> 160)
#define KP1  416   // padded K for layer-1 GEMM (400 -> 416)

typedef _Float16 half8 __attribute__((ext_vector_type(8)));
typedef _Float16 half4 __attribute__((ext_vector_type(4)));
typedef float    f32x4 __attribute__((ext_vector_type(4)));

__device__ __forceinline__ float frcp_(float x) { return __builtin_amdgcn_rcpf(x); }
__device__ __forceinline__ float sigm_(float x) { return frcp_(1.0f + __expf(-x)); }
__device__ __forceinline__ float tanh_(float x) { return 1.0f - 2.0f * frcp_(1.0f + __expf(2.0f * x)); }

// ---------------- embedding gather -> fp16 x (B*L, KP0), pads zeroed
__global__ void k_embed(const int* __restrict__ words, const int* __restrict__ caps,
                        const float* __restrict__ wemb, const float* __restrict__ cemb,
                        _Float16* __restrict__ x) {
    int pos = blockIdx.x;
    int w = words[pos], c = caps[pos];
    _Float16* xp = x + (size_t)pos * KP0;
    for (int t = threadIdx.x; t < KP0; t += blockDim.x) {
        float v = 0.f;
        if (t < DW_) v = wemb[(size_t)w * DW_ + t];
        else if (t < DW_ + DC_) v = cemb[(size_t)c * DC_ + (t - DW_)];
        xp[t] = (_Float16)v;
    }
}

// ---------------- W_ih prep: src (800,K) fp32 -> dst fp16 (1600, Kpad), col = colOff + 4*jh + g
__global__ void k_perm_ih16(const float* __restrict__ src, _Float16* __restrict__ dst,
                            int K, int Kpad, int colOff) {
    int i = blockIdx.x * blockDim.x + threadIdx.x;
    if (i >= 800 * Kpad) return;
    int r = i / Kpad, k = i - r * Kpad;
    int jh = r % 200, g = r / 200;
    int col = colOff + (jh << 2) + g;
    dst[(size_t)col * Kpad + k] = (k < K) ? (_Float16)src[(size_t)r * K + k] : (_Float16)0.f;
}

__global__ void k_bias_perm(const float* bi_f, const float* bh_f,
                            const float* bi_b, const float* bh_b, float* bias) {
    int j = blockIdx.x * blockDim.x + threadIdx.x;
    if (j >= 1600) return;
    int dir = j / 800, r = j - dir * 800;
    int col = dir * 800 + ((r % 200) << 2) + (r / 200);
    bias[col] = dir ? (bi_b[r] + bh_b[r]) : (bi_f[r] + bh_f[r]);
}

__global__ void k_wlog(const float* __restrict__ Wf, const float* __restrict__ bfv,
                       const float* __restrict__ Wb, const float* __restrict__ bbv,
                       float* __restrict__ wlog, float* __restrict__ blog) {
    int i = blockIdx.x * blockDim.x + threadIdx.x;
    if (i < NT_ * 400) {
        int t = i / 400, k = i - t * 400;
        wlog[i] = (k < HD_) ? Wf[t * HD_ + k] : Wb[t * HD_ + (k - HD_)];
    }
    if (i < NT_) blog[i] = bfv[i] + bbv[i];
}

// ---------------- MFMA fp16 GEMM: C(M,1600) = A(M,Kpad) @ Bt(1600,Kpad)^T + bias
__global__ __launch_bounds__(256) void k_gemm16(const _Float16* __restrict__ A,
                                                const _Float16* __restrict__ Bt,
                                                const float* __restrict__ bias,
                                                _Float16* __restrict__ C,
                                                int Kpad) {
    __shared__ __align__(16) _Float16 sA[128 * 40];
    __shared__ __align__(16) _Float16 sB[64 * 40];
    const int tid = threadIdx.x;
    const int w = tid >> 6, l = tid & 63, l15 = l & 15, lq = l >> 4;
    const int m0 = blockIdx.y * 128, n0 = blockIdx.x * 64;
    const int rw = (w >> 1) * 64, cw = (w & 1) * 32;
    f32x4 acc[4][2];
    #pragma unroll
    for (int i = 0; i < 4; i++)
        #pragma unroll
        for (int j = 0; j < 2; j++) acc[i][j] = f32x4{0.f, 0.f, 0.f, 0.f};

    for (int k0 = 0; k0 < Kpad; k0 += 32) {
        {
            int m = tid >> 1, c = (tid & 1) << 4;
            const _Float16* ap = A + (size_t)(m0 + m) * Kpad + k0 + c;
            *(half8*)&sA[m * 40 + c]     = *(const half8*)ap;
            *(half8*)&sA[m * 40 + c + 8] = *(const half8*)(ap + 8);
        }
        {
            int n = tid >> 2, k8 = (tid & 3) << 3;
            *(half8*)&sB[n * 40 + k8] = *(const half8*)&Bt[(size_t)(n0 + n) * Kpad + k0 + k8];
        }
        __syncthreads();
        half8 aF[4], bF[2];
        #pragma unroll
        for (int i = 0; i < 4; i++) aF[i] = *(const half8*)&sA[(rw + i * 16 + l15) * 40 + lq * 8];
        #pragma unroll
        for (int j = 0; j < 2; j++) bF[j] = *(const half8*)&sB[(cw + j * 16 + l15) * 40 + lq * 8];
        #pragma unroll
        for (int i = 0; i < 4; i++)
            #pragma unroll
            for (int j = 0; j < 2; j++)
                acc[i][j] = __builtin_amdgcn_mfma_f32_16x16x32_f16(aF[i], bF[j], acc[i][j], 0, 0, 0);
        __syncthreads();
    }
    #pragma unroll
    for (int j = 0; j < 2; j++) {
        int n = n0 + cw + j * 16 + l15;
        float bv = bias[n];
        #pragma unroll
        for (int i = 0; i < 4; i++) {
            int mrow = m0 + rw + i * 16 + lq * 4;
            #pragma unroll
            for (int r = 0; r < 4; r++)
                C[(size_t)(mrow + r) * 1600 + n] = (_Float16)(acc[i][j][r] + bv);
        }
    }
}

// ---------------- MFMA LSTM scan v6: transposed MFMA (D = W @ h^T) +
// one-b128-hop redistribution so the nonlinearity runs on all 64 lanes.
// gates: (B,L,1600) fp16, cols = dir*800 + 4*h + gate(i,f,g,o)
// hout: fp16 (B*L, ldH); dir0 -> cols [0,200), dir1 -> [200,400); masked
__global__ __launch_bounds__(512, 2) void k_scan6(const _Float16* __restrict__ gates,
                                                  const float* __restrict__ Whh_f,
                                                  const float* __restrict__ Whh_b,
                                                  const int* __restrict__ seq_len,
                                                  _Float16* __restrict__ hout, int ldH) {
    const int dir = blockIdx.x & 1;
    const int b0  = (blockIdx.x >> 1) * SG;
    const int tid = threadIdx.x;
    const int w   = tid >> 6;
    const int l   = tid & 63;
    const int l15 = l & 15;
    const int lq  = l >> 4;

    __shared__ __align__(16) _Float16 hA[2][16 * 232];   // ping-pong h state [p][m*232+k]
    __shared__ __align__(16) _Float16 bEx[2 * 7 * 512];  // W-frags tiles 48,49 (waves 0,1)
    __shared__ __align__(16) _Float16 glds[2][3200];     // staged gates [buf][m*800 + col]
    __shared__ __align__(16) float    gD[8 * 448];       // per-wave gate sums [w*448 + cell*4 + g]
    __shared__ int ssl[SG];

    const float* W = dir ? Whh_b : Whh_f;
    const int nT = (w < 2) ? 7 : 6;
    const int nCell = nT * 16;          // cells owned by this wave

    // resident W-fragments (A-operand layout): 6 register tiles + tiles 48/49 in LDS
    half8 Breg[6][7];
    #pragma unroll
    for (int i = 0; i < 6; i++) {
        int n  = (w * 6 + i) * 16 + l15;
        int jh = n >> 2, g = n & 3;
        const float* Wr = W + (size_t)(g * 200 + jh) * 200;
        #pragma unroll
        for (int kt = 0; kt < 7; kt++) {
            int k0 = kt * 32 + lq * 8;
            half8 f;
            #pragma unroll
            for (int j = 0; j < 8; j++) {
                int k = k0 + j;
                f[j] = (k < 200) ? (_Float16)Wr[k] : (_Float16)0.f;
            }
            Breg[i][kt] = f;
        }
    }
    if (w < 2) {
        int n  = (48 + w) * 16 + l15;
        int jh = n >> 2, g = n & 3;
        const float* Wr = W + (size_t)(g * 200 + jh) * 200;
        for (int kt = 0; kt < 7; kt++) {
            int k0 = kt * 32 + lq * 8;
            half8 f;
            for (int j = 0; j < 8; j++) {
                int k = k0 + j;
                f[j] = (k < 200) ? (_Float16)Wr[k] : (_Float16)0.f;
            }
            *(half8*)&bEx[(w * 7 + kt) * 512 + l * 8] = f;
        }
    }
    for (int i = tid; i < 2 * 16 * 232; i += 512) (&hA[0][0])[i] = (_Float16)0.f;
    if (tid < SG) ssl[tid] = seq_len[b0 + tid];

    // staging lane identity: lane v stages 16B of gate row m_st
    const int  v    = tid;
    const bool stv  = v < 400;
    const int  m_st = v / 100;
    const int  u_st = v - m_st * 100;
    const int  sl_st = stv ? seq_len[b0 + m_st] : L_;
    const _Float16* gbase_st = gates + ((size_t)(b0 + m_st) * L_) * 1600 + dir * 800 + u_st * 8;

    // nonlinearity cell identities: lane handles cells cA = l, cB = l + 64 (wave-local)
    // cell c -> tile slot i = c>>4, sub-row r = c&15; r = 4*q + m (q = sub-hidden, m = batch)
    const int cA = l;
    const int iA = cA >> 4, qA = (cA >> 2) & 3, mA = cA & 3;
    const int tgA = (iA < 6) ? (w * 6 + iA) : (48 + w);   // iA<4 always, so reg tile
    const int hcA = tgA * 4 + qA;
    const int cB = l + 64;
    const int iB = cB >> 4, qB = (cB >> 2) & 3, mB = cB & 3;
    const bool vB = cB < nCell;
    const int tgB = (iB < 6) ? (w * 6 + iB) : (48 + w);
    const int hcB = tgB * 4 + qB;
    float csA = 0.f, csB = 0.f;

    // stage t=0
    if (stv) {
        int rn = dir ? ((sl_st > 0) ? sl_st - 1 : 0) : 0;
        half8 stg = *(const half8*)(gbase_st + (size_t)rn * 1600);
        *(half8*)&glds[0][v * 8] = stg;
    }
    __syncthreads();

    const f32x4 Cz = {0.f, 0.f, 0.f, 0.f};
    for (int t = 0; t < L_; t++) {
        const int p = t & 1;

        // issue staging load for t+1 (committed to LDS at end of step)
        half8 stgn;
        const bool doStg = stv && (t + 1 < L_);
        if (doStg) {
            int tn = t + 1;
            int rn = dir ? ((tn < sl_st) ? sl_st - 1 - tn : tn) : tn;
            stgn = *(const half8*)(gbase_st + (size_t)rn * 1600);
        }

        // coalesced writeback of h(t-1) from hA[p]: 400 lanes x 1 dword
        if (t > 0 && stv) {
            int tp = t - 1;
            int b  = m_st;
            int hp = u_st;
            int slb = ssl[b];
            int row = dir ? ((tp < slb) ? slb - 1 - tp : tp) : tp;
            unsigned int val = (tp < slb) ? *(const unsigned int*)&hA[p][b * 232 + 2 * hp] : 0u;
            *(unsigned int*)&hout[((size_t)(b0 + b) * L_ + row) * ldH + dir * HD_ + 2 * hp] = val;
        }

        // MFMA: D = W @ h(t-1)^T  (A = W-frag, B = h-frag; D col = batch, row = 4*jh+gate)
        f32x4 C[7];
        #pragma unroll
        for (int i = 0; i < 7; i++) C[i] = Cz;
        #pragma unroll
        for (int kt = 0; kt < 7; kt++) {
            half8 hF = *(const half8*)&hA[p][l15 * 232 + kt * 32 + lq * 8];
            #pragma unroll
            for (int i = 0; i < 6; i++)
                C[i] = __builtin_amdgcn_mfma_f32_16x16x32_f16(Breg[i][kt], hF, C[i], 0, 0, 0);
            if (w < 2) {
                half8 bF = *(const half8*)&bEx[(w * 7 + kt) * 512 + l * 8];
                C[6] = __builtin_amdgcn_mfma_f32_16x16x32_f16(bF, hF, C[6], 0, 0, 0);
            }
        }

        // redistribute: active lanes (l15<4) hold 4 gates of cell (tile i, q=lq, m=l15)
        // contiguously -> single b128 per tile into the wave's gD region.
        if (l15 < 4) {
            #pragma unroll
            for (int i = 0; i < 6; i++)
                *(f32x4*)&gD[w * 448 + (i * 16 + lq * 4 + l15) * 4] = C[i];
            if (w < 2)
                *(f32x4*)&gD[w * 448 + (6 * 16 + lq * 4 + l15) * 4] = C[6];
        }

        // nonlinearity on all 64 lanes, ~1.75 cells each (same-wave LDS, no barrier)
        {
            f32x4 gv = *(const f32x4*)&gD[w * 448 + cA * 4];
            half4 gi4 = *(const half4*)&glds[p][mA * 800 + 4 * hcA];
            float xi = gv[0] + (float)gi4[0];
            float xf = gv[1] + (float)gi4[1];
            float xg = gv[2] + (float)gi4[2];
            float xo = gv[3] + (float)gi4[3];
            float cn = sigm_(xf) * csA + sigm_(xi) * tanh_(xg);
            csA = cn;
            hA[1 - p][mA * 232 + hcA] = (_Float16)(sigm_(xo) * tanh_(cn));
        }
        if (vB) {
            f32x4 gv = *(const f32x4*)&gD[w * 448 + cB * 4];
            half4 gi4 = *(const half4*)&glds[p][mB * 800 + 4 * hcB];
            float xi = gv[0] + (float)gi4[0];
            float xf = gv[1] + (float)gi4[1];
            float xg = gv[2] + (float)gi4[2];
            float xo = gv[3] + (float)gi4[3];
            float cn = sigm_(xf) * csB + sigm_(xi) * tanh_(xg);
            csB = cn;
            hA[1 - p][mB * 232 + hcB] = (_Float16)(sigm_(xo) * tanh_(cn));
        }

        // commit staged gates for t+1
        if (doStg) *(half8*)&glds[1 - p][v * 8] = stgn;

        __syncthreads();
    }
    // epilogue: write back h(L-1) from hA[0]
    if (stv) {
        int tp = L_ - 1;
        int b  = m_st;
        int hp = u_st;
        int slb = ssl[b];
        int row = dir ? ((tp < slb) ? slb - 1 - tp : tp) : tp;
        unsigned int val = (tp < slb) ? *(const unsigned int*)&hA[0][b * 232 + 2 * hp] : 0u;
        *(unsigned int*)&hout[((size_t)(b0 + b) * L_ + row) * ldH + dir * HD_ + 2 * hp] = val;
    }
}

// ---------------- logits: (B*L,18) = h1(B*L,400 fp16) @ wlog^T + blog
__global__ __launch_bounds__(256) void k_logits(const _Float16* __restrict__ h1,
                                                const float* __restrict__ wlog,
                                                const float* __restrict__ blog,
                                                float* __restrict__ logits) {
    __shared__ float sh[8][400];
    __shared__ float sw[NT_ * 400];
    int p0 = blockIdx.x * 8;
    for (int i = threadIdx.x; i < 8 * 400; i += 256)
        sh[i / 400][i % 400] = (float)h1[(size_t)p0 * 400 + i];
    for (int i = threadIdx.x; i < NT_ * 400; i += 256) sw[i] = wlog[i];
    __syncthreads();
    if (threadIdx.x < 8 * NT_) {
        int pi = threadIdx.x / NT_, tg = threadIdx.x % NT_;
        float a = blog[tg];
        #pragma unroll 4
        for (int k = 0; k < 400; k++) a += sh[pi][k] * sw[tg * 400 + k];
        logits[((size_t)(p0 + pi)) * NT_ + tg] = a;
    }
}

// ---------------- CRF NLL per batch row
__global__ __launch_bounds__(64) void k_crf(const float* __restrict__ logits,
                                            const int* __restrict__ target,
                                            const int* __restrict__ seq_len,
                                            const float* __restrict__ trans,
                                            float* __restrict__ out) {
    int b = blockIdx.x, tid = threadIdx.x;
    __shared__ float str[NT_ * NT_];
    __shared__ float alpha[NT_];
    __shared__ float sgold[1];
    for (int i = tid; i < NT_ * NT_; i += 64) str[i] = trans[i];
    int sl = seq_len[b];
    const float* lg = logits + (size_t)b * L_ * NT_;
    const int* tg = target + (size_t)b * L_;
    if (tid < NT_) alpha[tid] = lg[tid];
    float gacc = 0.f;
    for (int t = tid; t < L_; t += 64) {
        if (t < sl) {
            gacc += lg[t * NT_ + tg[t]];
            if (t >= 1) gacc += trans[tg[t - 1] * NT_ + tg[t]];
        }
    }
    #pragma unroll
    for (int off = 32; off; off >>= 1) gacc += __shfl_down(gacc, off);
    if (tid == 0) sgold[0] = gacc;
    __syncthreads();
    for (int t = 1; t < L_; t++) {
        if (t < sl) {
            float vv = 0.f;
            if (tid < NT_) {
                float mx = -1e30f;
                #pragma unroll
                for (int i = 0; i < NT_; i++) mx = fmaxf(mx, alpha[i] + str[i * NT_ + tid]);
                float s = 0.f;
                #pragma unroll
                for (int i = 0; i < NT_; i++) s += __expf(alpha[i] + str[i * NT_ + tid] - mx);
                vv = mx + __logf(s) + lg[t * NT_ + tid];
            }
            __syncthreads();
            if (tid < NT_) alpha[tid] = vv;
            __syncthreads();
        }
    }
    if (tid == 0) {
        float mx = -1e30f;
        for (int i = 0; i < NT_; i++) mx = fmaxf(mx, alpha[i]);
        float s = 0.f;
        for (int i = 0; i < NT_; i++) s += __expf(alpha[i] - mx);
        out[b] = (mx + __logf(s)) - sgold[0];
    }
}

extern "C" void kernel_launch(void* const* d_in, const int* in_sizes, int n_in,
                              void* d_out, int out_size, void* d_ws, size_t ws_size,
                              hipStream_t stream) {
    const int*   words  = (const int*)d_in[0];
    const int*   caps   = (const int*)d_in[1];
    const int*   seq    = (const int*)d_in[2];
    const int*   target = (const int*)d_in[3];
    const float* wemb   = (const float*)d_in[4];
    const float* cemb   = (const float*)d_in[5];
    const float* Wih0f  = (const float*)d_in[6];
    const float* Whh0f  = (const float*)d_in[7];
    const float* bih0f  = (const float*)d_in[8];
    const float* bhh0f  = (const float*)d_in[9];
    const float* Wih0b  = (const float*)d_in[10];
    const float* Whh0b  = (const float*)d_in[11];
    const float* bih0b  = (const float*)d_in[12];
    const float* bhh0b  = (const float*)d_in[13];
    const float* Wih1f  = (const float*)d_in[14];
    const float* Whh1f  = (const float*)d_in[15];
    const float* bih1f  = (const float*)d_in[16];
    const float* bhh1f  = (const float*)d_in[17];
    const float* Wih1b  = (const float*)d_in[18];
    const float* Whh1b  = (const float*)d_in[19];
    const float* bih1b  = (const float*)d_in[20];
    const float* bhh1b  = (const float*)d_in[21];
    const float* Wf     = (const float*)d_in[22];
    const float* bfv    = (const float*)d_in[23];
    const float* Wb     = (const float*)d_in[24];
    const float* bbv    = (const float*)d_in[25];
    const float* trans  = (const float*)d_in[26];

    char* base = (char*)d_ws;
    _Float16* gatesH = (_Float16*)(base + 0);                 // 104,857,600 B (32768x1600)
    _Float16* xbuf   = (_Float16*)(base + 104857600);         // 10,485,760 B (32768x160)
    _Float16* h0b    = (_Float16*)(base + 115343360);         // 27,262,976 B (32768x416)
    _Float16* h1b    = xbuf;  // 26,214,400 B needed; xbuf+h0 region dead by then
    float* logitsb   = (float*)(base + 142606336);            // 2,359,296 B
    _Float16* wihT0  = (_Float16*)(base + 144965632);         // 512,000 B (1600x160)
    _Float16* wihT1  = (_Float16*)(base + 145477632);         // 1,331,200 B (1600x416)
    float* bias0     = (float*)(base + 146808832);            // 6,400 B
    float* bias1     = (float*)(base + 146815232);            // 6,400 B
    float* wlog      = (float*)(base + 146821632);            // 28,800 B
    float* blog      = (float*)(base + 146850432);            // 128 B

    // --- weight prep
    k_perm_ih16<<<(800 * KP0 + 255) / 256, 256, 0, stream>>>(Wih0f, wihT0, 130, KP0, 0);
    k_perm_ih16<<<(800 * KP0 + 255) / 256, 256, 0, stream>>>(Wih0b, wihT0, 130, KP0, 800);
    k_perm_ih16<<<(800 * KP1 + 255) / 256, 256, 0, stream>>>(Wih1f, wihT1, 400, KP1, 0);
    k_perm_ih16<<<(800 * KP1 + 255) / 256, 256, 0, stream>>>(Wih1b, wihT1, 400, KP1, 800);
    k_bias_perm<<<7, 256, 0, stream>>>(bih0f, bhh0f, bih0b, bhh0b, bias0);
    k_bias_perm<<<7, 256, 0, stream>>>(bih1f, bhh1f, bih1b, bhh1b, bias1);
    k_wlog<<<(NT_ * 400 + 255) / 256, 256, 0, stream>>>(Wf, bfv, Wb, bbv, wlog, blog);

    // --- embeddings (fp16, padded)
    k_embed<<<B_ * L_, 128, 0, stream>>>(words, caps, wemb, cemb, xbuf);

    // zero h0 (its K-pad cols 400..415 must be 0 for the layer-1 GEMM)
    hipMemsetAsync(h0b, 0, (size_t)32768 * KP1 * sizeof(_Float16), stream);

    // --- layer 0
    k_gemm16<<<dim3(25, 256), 256, 0, stream>>>(xbuf, wihT0, bias0, gatesH, KP0);
    k_scan6<<<(B_ / SG) * 2, 512, 0, stream>>>(gatesH, Whh0f, Whh0b, seq, h0b, KP1);

    // --- layer 1
    k_gemm16<<<dim3(25, 256), 256, 0, stream>>>(h0b, wihT1, bias1, gatesH, KP1);
    k_scan6<<<(B_ / SG) * 2, 512, 0, stream>>>(gatesH, Whh1f, Whh1b, seq, h1b, 400);

    // --- logits + CRF
    k_logits<<<(B_ * L_) / 8, 256, 0, stream>>>(h1b, wlog, blog, logitsb);
    k_crf<<<B_, 64, 0, stream>>>(logitsb, target, seq, trans, (float*)d_out);
}